// Round 7
// baseline (216.138 us; speedup 1.0000x reference)
//
#include <hip/hip_runtime.h>

// Bilinear backward warp, NCHW f32 — direct paired gathers, enforced MLP.
// Wave = 16x4 pixel tile; paired-corner dwordx2 gathers, clamps folded into
// weights. Channel loop: two halves of 16 channels; each half issues ALL 32
// paired loads before any FMA (sched_barrier(0) pins the schedule — the
// compiler collapsed this in R4, VGPR stayed 32). ALL stores deferred to the
// end so no load s_waitcnt ever drains store retirement. XCD band swizzle.

#define NTHREADS 256

struct __attribute__((packed, aligned(4))) f2u { float lo, hi; };

__global__ __launch_bounds__(NTHREADS, 4) void warp_pf(
    const float* __restrict__ img,
    const float* __restrict__ flow,
    const int* __restrict__ Hp,
    const int* __restrict__ Wp,
    float* __restrict__ out,
    int HW, int C)
{
    const int W = *Wp;
    const int H = *Hp;
    const int tilesX = (W + 15) >> 4;
    const int tilesY = (H + 15) >> 4;
    const int ntiles = tilesX * tilesY;

    const int bid = blockIdx.x;
    if (bid >= ntiles) return;

    // bijective XCD band swizzle: each XCD gets a contiguous band of tiles
    const int q = ntiles >> 3, r = ntiles & 7;
    const int xcd = bid & 7, sub = bid >> 3;
    const int t = (xcd < r ? xcd * (q + 1) : r * (q + 1) + (xcd - r) * q) + sub;

    const int tileY = t / tilesX;
    const int tileX = t - tileY * tilesX;

    const int lane = threadIdx.x & 63;
    const int wv   = threadIdx.x >> 6;
    const int lx   = lane & 15;
    const int ly   = lane >> 4;

    const int gx = tileX * 16 + lx;
    const int gy = tileY * 16 + wv * 4 + ly;
    if (gx >= W || gy >= H) return;

    const int pix = gy * W + gx;

    const float u = flow[pix];
    const float v = flow[HW + pix];

    const float Wm1 = (float)(W - 1);
    const float Hm1 = (float)(H - 1);

    // reference's normalize/denormalize round-trip, replicated op-for-op
    float x = (float)gx + u;
    float y = (float)gy + v;
    x = 2.0f * (x / Wm1 - 0.5f);
    y = 2.0f * (y / Hm1 - 0.5f);
    x = (x + 1.0f) * 0.5f * Wm1;
    y = (y + 1.0f) * 0.5f * Hm1;

    const float x0 = floorf(x), x1 = x0 + 1.0f;
    const float y0 = floorf(y), y1 = y0 + 1.0f;

    const int x0c = (int)fminf(fmaxf(x0, 0.0f), Wm1);
    const int x1c = (int)fminf(fmaxf(x1, 0.0f), Wm1);
    const int y0c = (int)fminf(fmaxf(y0, 0.0f), Hm1);
    const int y1c = (int)fminf(fmaxf(y1, 0.0f), Hm1);

    // weights from UNclipped coords (reference semantics)
    const float wa = (x1 - x) * (y1 - y);
    const float wb = (x1 - x) * (y - y0);
    const float wc = (x - x0) * (y1 - y);
    const float wd = (x - x0) * (y - y0);

    // pair base column: covers {x0c, x1c} within [pb, pb+1]
    const int pb = min(x0c, W - 2);

    // fold lo/hi selection (incl. clamps) into per-row weight pairs
    const float wlo_t = (x0c == pb ? wa : 0.0f) + (x1c == pb ? wc : 0.0f);
    const float whi_t = (x0c != pb ? wa : 0.0f) + (x1c != pb ? wc : 0.0f);
    const float wlo_b = (x0c == pb ? wb : 0.0f) + (x1c == pb ? wd : 0.0f);
    const float whi_b = (x0c != pb ? wb : 0.0f) + (x1c != pb ? wd : 0.0f);

    const float* rt = img + (size_t)y0c * (size_t)W + pb;
    const float* rb = img + (size_t)y1c * (size_t)W + pb;
    float* po = out + pix;

    if (C == 32) {
        float res[32];
        f2u ta[16], tb[16];

        // ---- half 0: issue all 32 paired loads, then FMA ----
        #pragma unroll
        for (int k = 0; k < 16; ++k) {
            ta[k] = *(const f2u*)(rt + (size_t)k * (size_t)HW);
            tb[k] = *(const f2u*)(rb + (size_t)k * (size_t)HW);
        }
        __builtin_amdgcn_sched_barrier(0);
        #pragma unroll
        for (int k = 0; k < 16; ++k)
            res[k] = wlo_t * ta[k].lo + whi_t * ta[k].hi
                   + wlo_b * tb[k].lo + whi_b * tb[k].hi;

        // ---- half 1 ----
        #pragma unroll
        for (int k = 0; k < 16; ++k) {
            ta[k] = *(const f2u*)(rt + (size_t)(16 + k) * (size_t)HW);
            tb[k] = *(const f2u*)(rb + (size_t)(16 + k) * (size_t)HW);
        }
        __builtin_amdgcn_sched_barrier(0);
        #pragma unroll
        for (int k = 0; k < 16; ++k)
            res[16 + k] = wlo_t * ta[k].lo + whi_t * ta[k].hi
                        + wlo_b * tb[k].lo + whi_b * tb[k].hi;

        // ---- stores last: no load-wait ever includes a store ----
        __builtin_amdgcn_sched_barrier(0);
        #pragma unroll
        for (int k = 0; k < 32; ++k)
            po[(size_t)k * (size_t)HW] = res[k];
    } else {
        for (int c = 0; c < C; ++c) {
            const size_t off = (size_t)c * (size_t)HW;
            const f2u tp = *(const f2u*)(rt + off);
            const f2u bp = *(const f2u*)(rb + off);
            po[off] = wlo_t * tp.lo + whi_t * tp.hi
                    + wlo_b * bp.lo + whi_b * bp.hi;
        }
    }
}

extern "C" void kernel_launch(void* const* d_in, const int* in_sizes, int n_in,
                              void* d_out, int out_size, void* d_ws, size_t ws_size,
                              hipStream_t stream) {
    const float* img  = (const float*)d_in[0];
    const float* flow = (const float*)d_in[1];
    const int*   Hp   = (const int*)d_in[2];
    const int*   Wp   = (const int*)d_in[3];
    float* out = (float*)d_out;

    const int HW = in_sizes[1] / 2;    // flow is (1,2,H,W)
    const int C  = in_sizes[0] / HW;   // img is (1,C,H,W)

    const int grid = (HW + 255) / 256 + 2048;  // slack; extras exit on guard
    warp_pf<<<grid, NTHREADS, 0, stream>>>(img, flow, Hp, Wp, out, HW, C);
}

// Round 8
// 183.011 us; speedup vs baseline: 1.1810x; 1.1810x over previous
//
#include <hip/hip_runtime.h>

// Bilinear backward warp, NCHW f32 — LDS-tiled gather, slimmed.
// Block = (64x32 tile, 4-channel group). Stage 4 halo'd 80x48 planes into LDS
// via global_load_lds width-16 DMA (no VGPR round-trip, no ds_write
// conflicts), ONE __syncthreads, then pointer-marching gather:
// per (row,channel): 4 ds_read_b32 + 4 FMA + 1 coalesced store.
// cg = bid%8 aligns channel-group with XCD. R5 measured VALUBusy 39% +
// 1.5e7 LDS-conflict cycles from addressing fat + staged b128 writes; this
// version removes both.

#define TSX 64
#define TSY 32
#define RAD 8
#define LW  80          // TSX + 2*RAD
#define LH  48          // TSY + 2*RAD
#define PLANE (LW*LH)   // 3840 floats = 15360 B
#define CG  4
#define NTHREADS 512

#define GLOAD_LDS16(g, l)                                                  \
    __builtin_amdgcn_global_load_lds(                                      \
        (const __attribute__((address_space(1))) void*)(g),                \
        (__attribute__((address_space(3))) void*)(l), 16, 0, 0)

__global__ __launch_bounds__(NTHREADS) void warp_lds_dma(
    const float* __restrict__ img,
    const float* __restrict__ flow,
    const int* __restrict__ Hp,
    const int* __restrict__ Wp,
    float* __restrict__ out,
    int HW, int C, int NCG)
{
    __shared__ __align__(16) float lds[CG * PLANE];

    const int W = *Wp;
    const int H = *Hp;
    const int tilesX = (W + TSX - 1) / TSX;
    const int tilesY = (H + TSY - 1) / TSY;
    const int ntiles = tilesX * tilesY;

    const int cg = blockIdx.x % NCG;      // == XCD id under %8 round-robin
    const int t  = blockIdx.x / NCG;
    if (t >= ntiles) return;

    const int tileY = t / tilesX;
    const int tileX = t - tileY * tilesX;
    const int gx0 = tileX * TSX - RAD;
    const int gy0 = tileY * TSY - RAD;

    const int tid = threadIdx.x;
    const int lx  = tid & 63;
    const int wv  = tid >> 6;             // wave 0..7 -> rows wv*4 .. wv*4+3

    const int c0 = cg * CG;
    const int nc = min(CG, C - c0);

    const float Wm1 = (float)(W - 1);
    const float Hm1 = (float)(H - 1);
    const int gx = tileX * TSX + lx;

    // ---- per-pixel precompute: folded weights + LDS offset + out ptr ----
    float w0[4], w1[4], w2[4], w3[4];
    int   enc[4];    // la | dy<<12 ; -1 = global fallback; -2 = skip
    int   pixk[4];
    #pragma unroll
    for (int k = 0; k < 4; ++k) {
        const int gy = tileY * TSY + wv * 4 + k;
        if (gx >= W || gy >= H) { enc[k] = -2; continue; }
        const int pix = gy * W + gx;
        pixk[k] = pix;
        const float u = flow[pix];
        const float v = flow[HW + pix];

        // reference's normalize/denormalize round-trip, op-for-op
        float x = (float)gx + u;
        float y = (float)gy + v;
        x = 2.0f * (x / Wm1 - 0.5f);
        y = 2.0f * (y / Hm1 - 0.5f);
        x = (x + 1.0f) * 0.5f * Wm1;
        y = (y + 1.0f) * 0.5f * Hm1;

        const float x0 = floorf(x), x1 = x0 + 1.0f;
        const float y0 = floorf(y), y1 = y0 + 1.0f;

        const int x0c = (int)fminf(fmaxf(x0, 0.0f), Wm1);
        const int x1c = (int)fminf(fmaxf(x1, 0.0f), Wm1);
        const int y0c = (int)fminf(fmaxf(y0, 0.0f), Hm1);
        const int y1c = (int)fminf(fmaxf(y1, 0.0f), Hm1);

        const float wa = (x1 - x) * (y1 - y);
        const float wb = (x1 - x) * (y - y0);
        const float wc = (x - x0) * (y1 - y);
        const float wd = (x - x0) * (y - y0);

        const int pb = min(x0c, W - 2);   // pair base covers {x0c, x1c}
        w0[k] = (x0c == pb ? wa : 0.0f) + (x1c == pb ? wc : 0.0f);  // top lo
        w1[k] = (x0c != pb ? wa : 0.0f) + (x1c != pb ? wc : 0.0f);  // top hi
        w2[k] = (x0c == pb ? wb : 0.0f) + (x1c == pb ? wd : 0.0f);  // bot lo
        w3[k] = (x0c != pb ? wb : 0.0f) + (x1c != pb ? wd : 0.0f);  // bot hi

        const int lxp = pb - gx0;
        const int ly0 = y0c - gy0;
        const int ly1 = y1c - gy0;
        if (lxp >= 0 && lxp + 1 < LW && ly0 >= 0 && ly1 < LH) {
            enc[k] = (ly0 * LW + lxp) | ((ly1 - ly0) << 12);
        } else {
            enc[k] = -1;
        }
    }

    // ---- stage nc halo'd planes into LDS ----
    const bool xint = (gx0 >= 0) && (gx0 + LW <= W) && ((W & 3) == 0);
    if (xint) {
        const int NV = LH * (LW / 4);             // 960 float4 groups / plane
        for (int i = tid; i < nc * NV; i += NTHREADS) {
            const int ch  = i / NV;
            const int rem = i - ch * NV;
            const int r   = rem / (LW / 4);
            const int g   = rem - r * (LW / 4);
            const int yy  = min(max(gy0 + r, 0), H - 1);
            const float* src = img + (size_t)(c0 + ch) * HW
                                   + (size_t)yy * W + (gx0 + 4 * g);
            // linear LDS dest = base + i*16B: matches wave-uniform + lane*16
            GLOAD_LDS16(src, &lds[i * 4]);
        }
    } else {
        for (int i = tid; i < nc * PLANE; i += NTHREADS) {
            const int ch  = i / PLANE;
            const int rem = i - ch * PLANE;
            const int r   = rem / LW;
            const int cc  = rem - r * LW;
            const int yy  = min(max(gy0 + r, 0), H - 1);
            const int xx  = min(max(gx0 + cc, 0), W - 1);
            lds[i] = img[(size_t)(c0 + ch) * HW + (size_t)yy * W + xx];
        }
    }

    __syncthreads();   // compiler emits s_waitcnt vmcnt(0) lgkmcnt(0) first

    // ---- gather from LDS + blend + store (pointer-marching, no muls) ----
    #pragma unroll
    for (int k = 0; k < 4; ++k) {
        const int e = enc[k];
        if (e == -2) continue;

        if (__builtin_expect(e >= 0, 1)) {
            const float* pt = lds + (e & 4095);
            const float* pbm = pt + ((e >> 12) & 1) * LW;
            float* o = out + (size_t)c0 * (size_t)HW + pixk[k];
            const float a0 = w0[k], a1 = w1[k], a2 = w2[k], a3 = w3[k];
            if (nc == CG) {
                #pragma unroll
                for (int c = 0; c < CG; ++c) {
                    const float lt = pt[0], ht = pt[1];
                    const float lb = pbm[0], hb = pbm[1];
                    *o = a0 * lt + a1 * ht + a2 * lb + a3 * hb;
                    pt += PLANE; pbm += PLANE; o += HW;
                }
            } else {
                for (int c = 0; c < nc; ++c) {
                    const float lt = pt[0], ht = pt[1];
                    const float lb = pbm[0], hb = pbm[1];
                    *o = a0 * lt + a1 * ht + a2 * lb + a3 * hb;
                    pt += PLANE; pbm += PLANE; o += HW;
                }
            }
        } else {
            // rare out-of-halo: full recompute + global gather
            const int pix = pixk[k];
            const int gy  = tileY * TSY + wv * 4 + k;
            const float u = flow[pix];
            const float v = flow[HW + pix];
            float x = (float)gx + u;
            float y = (float)gy + v;
            x = 2.0f * (x / Wm1 - 0.5f);
            y = 2.0f * (y / Hm1 - 0.5f);
            x = (x + 1.0f) * 0.5f * Wm1;
            y = (y + 1.0f) * 0.5f * Hm1;
            const float x0 = floorf(x), y0f = floorf(y);
            const int x0c = (int)fminf(fmaxf(x0, 0.0f), Wm1);
            const int x1c = (int)fminf(fmaxf(x0 + 1.0f, 0.0f), Wm1);
            const int y0c = (int)fminf(fmaxf(y0f, 0.0f), Hm1);
            const int y1c = (int)fminf(fmaxf(y0f + 1.0f, 0.0f), Hm1);
            const float wa = (x0 + 1.0f - x) * (y0f + 1.0f - y);
            const float wb = (x0 + 1.0f - x) * (y - y0f);
            const float wc = (x - x0) * (y0f + 1.0f - y);
            const float wd = (x - x0) * (y - y0f);
            for (int c = 0; c < nc; ++c) {
                const float* ic = img + (size_t)(c0 + c) * HW;
                const float Ia = ic[(size_t)y0c * W + x0c];
                const float Ib = ic[(size_t)y1c * W + x0c];
                const float Ic = ic[(size_t)y0c * W + x1c];
                const float Id = ic[(size_t)y1c * W + x1c];
                out[(size_t)(c0 + c) * HW + pix] = wa*Ia + wb*Ib + wc*Ic + wd*Id;
            }
        }
    }
}

extern "C" void kernel_launch(void* const* d_in, const int* in_sizes, int n_in,
                              void* d_out, int out_size, void* d_ws, size_t ws_size,
                              hipStream_t stream) {
    const float* img  = (const float*)d_in[0];
    const float* flow = (const float*)d_in[1];
    const int*   Hp   = (const int*)d_in[2];
    const int*   Wp   = (const int*)d_in[3];
    float* out = (float*)d_out;

    const int HW = in_sizes[1] / 2;    // flow is (1,2,H,W)
    const int C  = in_sizes[0] / HW;   // img is (1,C,H,W)
    const int NCG = (C + CG - 1) / CG;

    // host doesn't know W,H (device scalars): launch with tile slack,
    // excess blocks exit on the in-kernel ntiles guard.
    const int maxt = (HW + TSX * TSY - 1) / (TSX * TSY) + 1024;
    const int grid = maxt * NCG;
    warp_lds_dma<<<grid, NTHREADS, 0, stream>>>(img, flow, Hp, Wp, out, HW, C, NCG);
}

// Round 9
// 150.716 us; speedup vs baseline: 1.4341x; 1.2143x over previous
//
#include <hip/hip_runtime.h>

// Bilinear backward warp, NCHW f32 — LDS-tiled gather via global_load_lds DMA.
// Block = (64x32 tile, 4-channel group), 1024 threads (16 waves) -> 2 blocks/CU
// = 32 waves/CU (R7 had 8-wave blocks: only 16 waves/CU, occupancy 42%).
// Per thread: 2 rows x 4 channels. Gather loop uses immediate-offset ds_read
// (c*PLANE fits 16-bit imm) — no pointer marching. Normalize/denormalize
// round-trip dropped (identity +-1 ulp; threshold 0.09 >> 1e-4 effect).

#define TSX 64
#define TSY 32
#define RAD 8
#define LW  80          // TSX + 2*RAD
#define LH  48          // TSY + 2*RAD
#define PLANE (LW*LH)   // 3840 floats = 15360 B
#define CG  4
#define KROWS 2
#define NTHREADS 1024

#define GLOAD_LDS16(g, l)                                                  \
    __builtin_amdgcn_global_load_lds(                                      \
        (const __attribute__((address_space(1))) void*)(g),                \
        (__attribute__((address_space(3))) void*)(l), 16, 0, 0)

__global__ __launch_bounds__(NTHREADS, 8) void warp_lds_dma2(
    const float* __restrict__ img,
    const float* __restrict__ flow,
    const int* __restrict__ Hp,
    const int* __restrict__ Wp,
    float* __restrict__ out,
    int HW, int C, int NCG)
{
    __shared__ __align__(16) float lds[CG * PLANE];

    const int W = *Wp;
    const int H = *Hp;
    const int tilesX = (W + TSX - 1) / TSX;
    const int tilesY = (H + TSY - 1) / TSY;
    const int ntiles = tilesX * tilesY;

    const int cg = blockIdx.x % NCG;      // == XCD id under %8 round-robin
    const int t  = blockIdx.x / NCG;
    if (t >= ntiles) return;

    const int tileY = t / tilesX;
    const int tileX = t - tileY * tilesX;
    const int gx0 = tileX * TSX - RAD;
    const int gy0 = tileY * TSY - RAD;

    const int tid = threadIdx.x;
    const int lx  = tid & 63;
    const int rw  = (tid >> 6) * KROWS;   // row base 0,2,..,30

    const int c0 = cg * CG;
    const int nc = min(CG, C - c0);

    const float Wm1 = (float)(W - 1);
    const float Hm1 = (float)(H - 1);
    const int gx = tileX * TSX + lx;

    // ---- per-pixel precompute: folded weights + LDS offset ----
    float w0[KROWS], w1[KROWS], w2[KROWS], w3[KROWS];
    int   enc[KROWS];    // la | dy<<12 ; -1 = global fallback; -2 = skip
    int   pixk[KROWS];
    #pragma unroll
    for (int k = 0; k < KROWS; ++k) {
        const int gy = tileY * TSY + rw + k;
        if (gx >= W || gy >= H) { enc[k] = -2; continue; }
        const int pix = gy * W + gx;
        pixk[k] = pix;
        const float u = flow[pix];
        const float v = flow[HW + pix];

        // normalize/denormalize round-trip omitted (identity, +-1 ulp)
        const float x = (float)gx + u;
        const float y = (float)gy + v;

        const float x0 = floorf(x), x1 = x0 + 1.0f;
        const float y0 = floorf(y), y1 = y0 + 1.0f;

        const int x0c = (int)fminf(fmaxf(x0, 0.0f), Wm1);
        const int x1c = (int)fminf(fmaxf(x1, 0.0f), Wm1);
        const int y0c = (int)fminf(fmaxf(y0, 0.0f), Hm1);
        const int y1c = (int)fminf(fmaxf(y1, 0.0f), Hm1);

        const float wa = (x1 - x) * (y1 - y);
        const float wb = (x1 - x) * (y - y0);
        const float wc = (x - x0) * (y1 - y);
        const float wd = (x - x0) * (y - y0);

        const int pb = min(x0c, W - 2);   // pair base covers {x0c, x1c}
        w0[k] = (x0c == pb ? wa : 0.0f) + (x1c == pb ? wc : 0.0f);  // top lo
        w1[k] = (x0c != pb ? wa : 0.0f) + (x1c != pb ? wc : 0.0f);  // top hi
        w2[k] = (x0c == pb ? wb : 0.0f) + (x1c == pb ? wd : 0.0f);  // bot lo
        w3[k] = (x0c != pb ? wb : 0.0f) + (x1c != pb ? wd : 0.0f);  // bot hi

        const int lxp = pb - gx0;
        const int ly0 = y0c - gy0;
        const int ly1 = y1c - gy0;
        if (lxp >= 0 && lxp + 1 < LW && ly0 >= 0 && ly1 < LH) {
            enc[k] = (ly0 * LW + lxp) | ((ly1 - ly0) << 12);
        } else {
            enc[k] = -1;
        }
    }

    // ---- stage nc halo'd planes into LDS via 16B DMA ----
    const bool xint = (gx0 >= 0) && (gx0 + LW <= W) && ((W & 3) == 0);
    if (xint) {
        const int NV = LH * (LW / 4);             // 960 float4 groups / plane
        for (int i = tid; i < nc * NV; i += NTHREADS) {
            const int ch  = i / NV;
            const int rem = i - ch * NV;
            const int r   = rem / (LW / 4);
            const int g   = rem - r * (LW / 4);
            const int yy  = min(max(gy0 + r, 0), H - 1);
            const float* src = img + (size_t)(c0 + ch) * HW
                                   + (size_t)yy * W + (gx0 + 4 * g);
            // linear LDS dest = base + i*16B: matches wave-uniform + lane*16
            GLOAD_LDS16(src, &lds[i * 4]);
        }
    } else {
        for (int i = tid; i < nc * PLANE; i += NTHREADS) {
            const int ch  = i / PLANE;
            const int rem = i - ch * PLANE;
            const int r   = rem / LW;
            const int cc  = rem - r * LW;
            const int yy  = min(max(gy0 + r, 0), H - 1);
            const int xx  = min(max(gx0 + cc, 0), W - 1);
            lds[i] = img[(size_t)(c0 + ch) * HW + (size_t)yy * W + xx];
        }
    }

    __syncthreads();

    // ---- gather from LDS (imm-offset reads) + blend + store ----
    #pragma unroll
    for (int k = 0; k < KROWS; ++k) {
        const int e = enc[k];
        if (e == -2) continue;

        if (__builtin_expect(e >= 0, 1)) {
            const float* bt = lds + (e & 4095);                 // top row base
            const float* bb = bt + ((e >> 12) & 1) * LW;        // bottom row
            float* o = out + (size_t)c0 * (size_t)HW + pixk[k];
            const float a0 = w0[k], a1 = w1[k], a2 = w2[k], a3 = w3[k];
            if (nc == CG) {
                #pragma unroll
                for (int c = 0; c < CG; ++c) {
                    const float lt = bt[c * PLANE], ht = bt[c * PLANE + 1];
                    const float lb = bb[c * PLANE], hb = bb[c * PLANE + 1];
                    o[(size_t)c * (size_t)HW] = a0*lt + a1*ht + a2*lb + a3*hb;
                }
            } else {
                for (int c = 0; c < nc; ++c) {
                    const float lt = bt[c * PLANE], ht = bt[c * PLANE + 1];
                    const float lb = bb[c * PLANE], hb = bb[c * PLANE + 1];
                    o[(size_t)c * (size_t)HW] = a0*lt + a1*ht + a2*lb + a3*hb;
                }
            }
        } else {
            // rare out-of-halo: recompute + global gather
            const int pix = pixk[k];
            const int gy  = tileY * TSY + rw + k;
            const float u = flow[pix];
            const float v = flow[HW + pix];
            const float x = (float)gx + u;
            const float y = (float)gy + v;
            const float x0 = floorf(x), y0f = floorf(y);
            const int x0c = (int)fminf(fmaxf(x0, 0.0f), Wm1);
            const int x1c = (int)fminf(fmaxf(x0 + 1.0f, 0.0f), Wm1);
            const int y0c = (int)fminf(fmaxf(y0f, 0.0f), Hm1);
            const int y1c = (int)fminf(fmaxf(y0f + 1.0f, 0.0f), Hm1);
            const float wa = (x0 + 1.0f - x) * (y0f + 1.0f - y);
            const float wb = (x0 + 1.0f - x) * (y - y0f);
            const float wc = (x - x0) * (y0f + 1.0f - y);
            const float wd = (x - x0) * (y - y0f);
            for (int c = 0; c < nc; ++c) {
                const float* ic = img + (size_t)(c0 + c) * HW;
                const float Ia = ic[(size_t)y0c * W + x0c];
                const float Ib = ic[(size_t)y1c * W + x0c];
                const float Ic = ic[(size_t)y0c * W + x1c];
                const float Id = ic[(size_t)y1c * W + x1c];
                out[(size_t)(c0 + c) * HW + pix] = wa*Ia + wb*Ib + wc*Ic + wd*Id;
            }
        }
    }
}

extern "C" void kernel_launch(void* const* d_in, const int* in_sizes, int n_in,
                              void* d_out, int out_size, void* d_ws, size_t ws_size,
                              hipStream_t stream) {
    const float* img  = (const float*)d_in[0];
    const float* flow = (const float*)d_in[1];
    const int*   Hp   = (const int*)d_in[2];
    const int*   Wp   = (const int*)d_in[3];
    float* out = (float*)d_out;

    const int HW = in_sizes[1] / 2;    // flow is (1,2,H,W)
    const int C  = in_sizes[0] / HW;   // img is (1,C,H,W)
    const int NCG = (C + CG - 1) / CG;

    // host doesn't know W,H (device scalars): launch with tile slack,
    // excess blocks exit on the in-kernel ntiles guard.
    const int maxt = (HW + TSX * TSY - 1) / (TSX * TSY) + 1024;
    const int grid = maxt * NCG;
    warp_lds_dma2<<<grid, NTHREADS, 0, stream>>>(img, flow, Hp, Wp, out, HW, C, NCG);
}

// Round 10
// 132.339 us; speedup vs baseline: 1.6332x; 1.1389x over previous
//
#include <hip/hip_runtime.h>

// Bilinear backward warp, NCHW f32 — one block per 64x32 tile, pipelined
// channel loop. LDS: 2 ping-pong buffers x 2 channel planes (80x48 halo'd).
// Per phase: issue DMA stage of NEXT 2 planes, then gather CURRENT 2 planes
// (its DMA was issued last phase and completes at this phase's barrier).
// Per-pixel precompute (flow, weights, enc) done ONCE per tile (was 8x in R8).
// Both x- and y-clamps folded into a 2x2 weight patch -> gather is
// 2x ds_read2_b32 {0,80},{1,81} + 4 FMA + 1 store per (px,ch).
// OOB halo cells are never read (clamped corners stay in-image), so the DMA
// source is just clamped -> single staging path, all global_load_lds.

#define TSX 64
#define TSY 32
#define RAD 8
#define LW  80           // TSX + 2*RAD
#define LH  48           // TSY + 2*RAD
#define PLANE (LW*LH)    // 3840 floats = 15360 B
#define CGB 2            // channels per buffer
#define NV (LH*(LW/4))   // 960 float4 groups per plane
#define NTHREADS 1024

#define GLOAD_LDS16(g, l)                                                  \
    __builtin_amdgcn_global_load_lds(                                      \
        (const __attribute__((address_space(1))) void*)(g),                \
        (__attribute__((address_space(3))) void*)(l), 16, 0, 0)

__global__ __launch_bounds__(NTHREADS, 8) void warp_pipe(
    const float* __restrict__ img,
    const float* __restrict__ flow,
    const int* __restrict__ Hp,
    const int* __restrict__ Wp,
    float* __restrict__ out,
    int HW, int C)
{
    __shared__ __align__(16) float lds[2][CGB * PLANE];   // 61440 B

    const int W = *Wp;
    const int H = *Hp;
    const int tilesX = (W + TSX - 1) / TSX;
    const int tilesY = (H + TSY - 1) / TSY;
    const int ntiles = tilesX * tilesY;
    const int bid = blockIdx.x;
    if (bid >= ntiles) return;

    // bijective XCD band swizzle
    const int q = ntiles >> 3, r = ntiles & 7;
    const int xcd = bid & 7, sub = bid >> 3;
    const int t = (xcd < r ? xcd * (q + 1) : r * (q + 1) + (xcd - r) * q) + sub;

    const int tileY = t / tilesX;
    const int tileX = t - tileY * tilesX;
    const int gx0 = tileX * TSX - RAD;
    const int gy0 = tileY * TSY - RAD;

    const int tid = threadIdx.x;
    const int lx  = tid & 63;
    const int rw  = (tid >> 6) * 2;       // 2 rows per thread
    const int gx  = tileX * TSX + lx;

    const float Wm1 = (float)(W - 1);
    const float Hm1 = (float)(H - 1);

    // ---- per-pixel precompute, ONCE per tile ----
    float wtl[2], wth[2], wbl[2], wbh[2];
    int   enc[2], pixk[2];
    #pragma unroll
    for (int k = 0; k < 2; ++k) {
        const int gy = tileY * TSY + rw + k;
        enc[k] = -2;
        if (gx >= W || gy >= H) continue;
        const int pix = gy * W + gx;
        pixk[k] = pix;
        const float u = flow[pix];
        const float v = flow[HW + pix];

        // normalize/denormalize round-trip omitted (identity, +-1 ulp)
        const float x = (float)gx + u;
        const float y = (float)gy + v;
        const float x0 = floorf(x), x1 = x0 + 1.0f;
        const float y0 = floorf(y), y1 = y0 + 1.0f;

        const int x0c = (int)fminf(fmaxf(x0, 0.0f), Wm1);
        const int x1c = (int)fminf(fmaxf(x1, 0.0f), Wm1);
        const int y0c = (int)fminf(fmaxf(y0, 0.0f), Hm1);
        const int y1c = (int)fminf(fmaxf(y1, 0.0f), Hm1);

        const float wa = (x1 - x) * (y1 - y);
        const float wb = (x1 - x) * (y - y0);
        const float wc = (x - x0) * (y1 - y);
        const float wd = (x - x0) * (y - y0);

        const int pbx = min(x0c, W - 2);   // x-pair base covers {x0c,x1c}
        const int pby = min(y0c, H - 2);   // y-pair base covers {y0c,y1c}

        // fold x-clamp selection
        const float wlt = (x0c == pbx ? wa : 0.f) + (x1c == pbx ? wc : 0.f);
        const float wht = (x0c != pbx ? wa : 0.f) + (x1c != pbx ? wc : 0.f);
        const float wlb = (x0c == pbx ? wb : 0.f) + (x1c == pbx ? wd : 0.f);
        const float whb = (x0c != pbx ? wb : 0.f) + (x1c != pbx ? wd : 0.f);
        // fold y-clamp selection
        const bool t0 = (y0c == pby), t1 = (y1c == pby);
        wtl[k] = (t0 ? wlt : 0.f) + (t1 ? wlb : 0.f);
        wth[k] = (t0 ? wht : 0.f) + (t1 ? whb : 0.f);
        wbl[k] = (t0 ? 0.f : wlt) + (t1 ? 0.f : wlb);
        wbh[k] = (t0 ? 0.f : wht) + (t1 ? 0.f : whb);

        const int lxp = pbx - gx0;
        const int lyb = pby - gy0;
        enc[k] = (lxp >= 0 && lxp <= LW - 2 && lyb >= 0 && lyb <= LH - 2)
               ? (lyb * LW + lxp) : -1;
    }

    const int nph = (C + CGB - 1) / CGB;

    // ---- stage phase 0 into buf 0 ----
    for (int i = tid; i < CGB * NV; i += NTHREADS) {
        const int ch  = i / NV;
        const int rem = i - ch * NV;
        const int rr  = rem / (LW / 4);
        const int g   = rem - rr * (LW / 4);
        const int yy  = min(max(gy0 + rr, 0), H - 1);
        const int xs  = min(max(gx0 + 4 * g, 0), W - 4);
        const int chc = min(ch, C - 1);
        GLOAD_LDS16(img + (size_t)chc * HW + (size_t)yy * W + xs,
                    &lds[0][i * 4]);
    }

    int buf = 0;
    for (int p = 0; p < nph; ++p) {
        __syncthreads();   // drains DMA for buf (issued last phase) + barrier

        const int c0 = p * CGB;

        // issue DMA for NEXT phase into other buffer (hidden under gather)
        if (p + 1 < nph) {
            const int c0n = (p + 1) * CGB;
            float* dst = &lds[buf ^ 1][0];
            for (int i = tid; i < CGB * NV; i += NTHREADS) {
                const int ch  = i / NV;
                const int rem = i - ch * NV;
                const int rr  = rem / (LW / 4);
                const int g   = rem - rr * (LW / 4);
                const int yy  = min(max(gy0 + rr, 0), H - 1);
                const int xs  = min(max(gx0 + 4 * g, 0), W - 4);
                const int chc = min(c0n + ch, C - 1);
                GLOAD_LDS16(img + (size_t)chc * HW + (size_t)yy * W + xs,
                            dst + i * 4);
            }
        }

        // gather current buffer
        const float* base = &lds[buf][0];
        #pragma unroll
        for (int k = 0; k < 2; ++k) {
            const int e = enc[k];
            if (e == -2) continue;

            if (__builtin_expect(e >= 0, 1)) {
                const float* b0 = base + e;
                #pragma unroll
                for (int c = 0; c < CGB; ++c) {
                    if (c0 + c >= C) break;
                    const float lt = b0[c * PLANE],      ht = b0[c * PLANE + 1];
                    const float lb = b0[c * PLANE + LW], hb = b0[c * PLANE + LW + 1];
                    out[(size_t)(c0 + c) * HW + pixk[k]] =
                        wtl[k] * lt + wth[k] * ht + wbl[k] * lb + wbh[k] * hb;
                }
            } else {
                // rare out-of-halo flow: recompute + global gather
                const int pix = pixk[k];
                const int gy  = tileY * TSY + rw + k;
                const float u = flow[pix];
                const float v = flow[HW + pix];
                const float x = (float)gx + u;
                const float y = (float)gy + v;
                const float x0 = floorf(x), y0f = floorf(y);
                const int x0c = (int)fminf(fmaxf(x0, 0.0f), Wm1);
                const int x1c = (int)fminf(fmaxf(x0 + 1.0f, 0.0f), Wm1);
                const int y0c = (int)fminf(fmaxf(y0f, 0.0f), Hm1);
                const int y1c = (int)fminf(fmaxf(y0f + 1.0f, 0.0f), Hm1);
                const float wa = (x0 + 1.0f - x) * (y0f + 1.0f - y);
                const float wb = (x0 + 1.0f - x) * (y - y0f);
                const float wc = (x - x0) * (y0f + 1.0f - y);
                const float wd = (x - x0) * (y - y0f);
                for (int c = 0; c < CGB && c0 + c < C; ++c) {
                    const float* ic = img + (size_t)(c0 + c) * HW;
                    const float Ia = ic[(size_t)y0c * W + x0c];
                    const float Ib = ic[(size_t)y1c * W + x0c];
                    const float Ic = ic[(size_t)y0c * W + x1c];
                    const float Id = ic[(size_t)y1c * W + x1c];
                    out[(size_t)(c0 + c) * HW + pix] = wa*Ia + wb*Ib + wc*Ic + wd*Id;
                }
            }
        }
        buf ^= 1;
    }
}

extern "C" void kernel_launch(void* const* d_in, const int* in_sizes, int n_in,
                              void* d_out, int out_size, void* d_ws, size_t ws_size,
                              hipStream_t stream) {
    const float* img  = (const float*)d_in[0];
    const float* flow = (const float*)d_in[1];
    const int*   Hp   = (const int*)d_in[2];
    const int*   Wp   = (const int*)d_in[3];
    float* out = (float*)d_out;

    const int HW = in_sizes[1] / 2;    // flow is (1,2,H,W)
    const int C  = in_sizes[0] / HW;   // img is (1,C,H,W)

    // host doesn't know W,H (device scalars): launch with tile slack,
    // excess blocks exit on the in-kernel ntiles guard.
    const int grid = (HW + TSX * TSY - 1) / (TSX * TSY) + 64;
    warp_pipe<<<grid, NTHREADS, 0, stream>>>(img, flow, Hp, Wp, out, HW, C);
}

// Round 12
// 126.898 us; speedup vs baseline: 1.7032x; 1.0429x over previous
//
#include <hip/hip_runtime.h>

// Bilinear backward warp, NCHW f32 — pipelined LDS channel loop, slimmed.
// Block = 64x32 tile, 1024 threads. LDS: 2 ping-pong buffers x 2 planes of
// (72x40) RAD=4 halo'd tile (46 KB total). Per phase: issue next-phase DMA
// (global_load_lds x2/thread, descriptors precomputed ONCE), gather current
// buffer, then counted s_waitcnt vmcnt(4) + raw s_barrier (output stores stay
// in flight; the 2 oldest VM ops = our DMAs are retired by in-order vmcnt).
//
// R10 BUG FIX: staging slot map must be lane-consecutive per wave with no
// wrap — global_load_lds writes wave-uniform base + lane*16, so an intra-wave
// slot discontinuity writes 16 slots PAST the buffer (corrupted the gather
// buffer). New map: s=0 -> slot tid (0..1023), s=1 -> slot 416+tid
// (416..1439). All 1440 slots covered; 416..1023 staged twice (same src,
// same dst — benign). No partial waves, no OOB.

#define TSX 64
#define TSY 32
#define RAD 4
#define LW  (TSX + 2*RAD)     // 72
#define LH  (TSY + 2*RAD)     // 40
#define GPR (LW/4)            // 18 float4 groups per row
#define PLANE (LW*LH)         // 2880 floats = 11520 B
#define NV  (LH*GPR)          // 720 groups per plane
#define CGB 2                 // channels per buffer
#define NSTG (CGB*NV)         // 1440 DMA slots per phase
#define NTHREADS 1024
#define SOFF (NSTG - NTHREADS)  // 416: second-slot offset

static_assert(NSTG >= NTHREADS && NSTG <= 2*NTHREADS, "2 slots per thread");

#define GLOAD_LDS16(g, l)                                                  \
    __builtin_amdgcn_global_load_lds(                                      \
        (const __attribute__((address_space(1))) void*)(g),                \
        (__attribute__((address_space(3))) void*)(l), 16, 0, 0)

__global__ __launch_bounds__(NTHREADS, 8) void warp_pipe3(
    const float* __restrict__ img,
    const float* __restrict__ flow,
    const int* __restrict__ Hp,
    const int* __restrict__ Wp,
    float* __restrict__ out,
    int HW, int C)
{
    __shared__ __align__(16) float lds[2 * CGB * PLANE];   // 46080 B

    const int W = *Wp;
    const int H = *Hp;
    const int tilesX = (W + TSX - 1) / TSX;
    const int tilesY = (H + TSY - 1) / TSY;
    const int ntiles = tilesX * tilesY;
    const int bid = blockIdx.x;
    if (bid >= ntiles) return;

    // bijective XCD band swizzle
    const int q = ntiles >> 3, r = ntiles & 7;
    const int xcd = bid & 7, sub = bid >> 3;
    const int t = (xcd < r ? xcd*(q+1) : r*(q+1) + (xcd-r)*q) + sub;

    const int tileY = t / tilesX;
    const int tileX = t - tileY * tilesX;
    const int gx0 = tileX * TSX - RAD;   // always ≡ 0 (mod 4)
    const int gy0 = tileY * TSY - RAD;

    const int tid = threadIdx.x;
    const int lx  = tid & 63;
    const int rw  = (tid >> 6) * 2;      // 2 rows per thread
    const int gx  = tileX * TSX + lx;

    const float Wm1 = (float)(W - 1);
    const float Hm1 = (float)(H - 1);

    // ---- per-pixel precompute (once per tile) ----
    float wtl[2], wth[2], wbl[2], wbh[2];
    int enc[2], pixk[2] = {0, 0};
    #pragma unroll
    for (int k = 0; k < 2; ++k) {
        const int gy = tileY * TSY + rw + k;
        enc[k] = -2;
        if (gx >= W || gy >= H) continue;
        const int pix = gy * W + gx;
        pixk[k] = pix;
        const float u = flow[pix];
        const float v = flow[HW + pix];

        // normalize/denormalize round-trip omitted (identity, +-1 ulp)
        const float x = (float)gx + u;
        const float y = (float)gy + v;
        const float x0 = floorf(x), x1 = x0 + 1.0f;
        const float y0 = floorf(y), y1 = y0 + 1.0f;

        const int x0c = (int)fminf(fmaxf(x0, 0.0f), Wm1);
        const int x1c = (int)fminf(fmaxf(x1, 0.0f), Wm1);
        const int y0c = (int)fminf(fmaxf(y0, 0.0f), Hm1);
        const int y1c = (int)fminf(fmaxf(y1, 0.0f), Hm1);

        const float wa = (x1 - x) * (y1 - y);
        const float wb = (x1 - x) * (y - y0);
        const float wc = (x - x0) * (y1 - y);
        const float wd = (x - x0) * (y - y0);

        const int pbx = min(x0c, W - 2);
        const int pby = min(y0c, H - 2);

        const float wlt = (x0c == pbx ? wa : 0.f) + (x1c == pbx ? wc : 0.f);
        const float wht = (x0c != pbx ? wa : 0.f) + (x1c != pbx ? wc : 0.f);
        const float wlb = (x0c == pbx ? wb : 0.f) + (x1c == pbx ? wd : 0.f);
        const float whb = (x0c != pbx ? wb : 0.f) + (x1c != pbx ? wd : 0.f);
        const bool t0 = (y0c == pby), t1 = (y1c == pby);
        wtl[k] = (t0 ? wlt : 0.f) + (t1 ? wlb : 0.f);
        wth[k] = (t0 ? wht : 0.f) + (t1 ? whb : 0.f);
        wbl[k] = (t0 ? 0.f : wlt) + (t1 ? 0.f : wlb);
        wbh[k] = (t0 ? 0.f : wht) + (t1 ? 0.f : whb);

        const int lxp = pbx - gx0;
        const int lyb = pby - gy0;
        enc[k] = (lxp >= 0 && lxp <= LW-2 && lyb >= 0 && lyb <= LH-2)
               ? (lyb * LW + lxp) : -1;
    }

    float* optr0 = out + pixk[0];
    float* optr1 = out + pixk[1];

    // ---- staging descriptors, computed once; lane-consecutive slots ----
    int spix[2], chrel[2], dst4[2];
    #pragma unroll
    for (int s = 0; s < 2; ++s) {
        const int idx = tid + s * SOFF;        // s=0: 0..1023, s=1: 416..1439
        const int ch  = idx / NV;
        const int rem = idx - ch * NV;
        const int rr  = rem / GPR;
        const int g   = rem - rr * GPR;
        const int yy  = min(max(gy0 + rr, 0), H - 1);
        const int xs  = min(max(gx0 + 4*g, 0), W - 4);  // group fully in/out
        chrel[s] = ch;
        spix[s]  = yy * W + xs;
        dst4[s]  = idx * 4;
    }

    const int nph = (C + CGB - 1) / CGB;
    const bool fast = ((W & 3) == 0) && ((tileX+1)*TSX <= W)
                   && ((tileY+1)*TSY <= H);

    // gather one phase from `cur`; stores via optr0/optr1
    auto gather2 = [&](const float* cur, int c0) {
        #pragma unroll
        for (int k = 0; k < 2; ++k) {
            const int e = enc[k];
            if (e == -2) continue;
            float* o = (k == 0) ? optr0 : optr1;
            if (__builtin_expect(e >= 0, 1)) {
                const float* b0 = cur + e;
                const float a0 = wtl[k], a1 = wth[k];
                const float a2 = wbl[k], a3 = wbh[k];
                o[0] = a0*b0[0] + a1*b0[1] + a2*b0[LW] + a3*b0[LW+1];
                if (c0 + 1 < C)
                    o[HW] = a0*b0[PLANE]   + a1*b0[PLANE+1]
                          + a2*b0[PLANE+LW] + a3*b0[PLANE+LW+1];
            } else {
                // rare out-of-halo flow: recompute + global gather
                const int pix = pixk[k];
                const int gy  = tileY * TSY + rw + k;
                const float u = flow[pix];
                const float v = flow[HW + pix];
                const float x = (float)gx + u;
                const float y = (float)gy + v;
                const float x0 = floorf(x), y0f = floorf(y);
                const int x0c = (int)fminf(fmaxf(x0, 0.f), Wm1);
                const int x1c = (int)fminf(fmaxf(x0 + 1.f, 0.f), Wm1);
                const int y0c = (int)fminf(fmaxf(y0f, 0.f), Hm1);
                const int y1c = (int)fminf(fmaxf(y0f + 1.f, 0.f), Hm1);
                const float wa = (x0 + 1.f - x) * (y0f + 1.f - y);
                const float wb = (x0 + 1.f - x) * (y - y0f);
                const float wc = (x - x0) * (y0f + 1.f - y);
                const float wd = (x - x0) * (y - y0f);
                for (int c = 0; c < CGB && c0 + c < C; ++c) {
                    const float* ic = img + (size_t)(c0 + c) * HW;
                    o[(size_t)c * HW] =
                          wa * ic[(size_t)y0c*W + x0c] + wb * ic[(size_t)y1c*W + x0c]
                        + wc * ic[(size_t)y0c*W + x1c] + wd * ic[(size_t)y1c*W + x1c];
                }
            }
        }
    };

    if (fast) {
        // prologue: stage phase 0 into buffer A
        #pragma unroll
        for (int s = 0; s < 2; ++s) {
            const int chc = min(chrel[s], C - 1);
            GLOAD_LDS16(img + (size_t)chc * HW + spix[s], &lds[dst4[s]]);
        }
        asm volatile("s_waitcnt vmcnt(0)" ::: "memory");
        __builtin_amdgcn_s_barrier();
        __builtin_amdgcn_sched_barrier(0);

        float* cur = &lds[0];
        float* nxt = &lds[CGB * PLANE];

        for (int p = 0; p < nph; ++p) {
            const int c0 = p * CGB;

            if (p + 1 < nph) {   // issue DMA for next phase FIRST
                const int c0n = c0 + CGB;
                #pragma unroll
                for (int s = 0; s < 2; ++s) {
                    const int chc = min(c0n + chrel[s], C - 1);
                    GLOAD_LDS16(img + (size_t)chc * HW + spix[s], nxt + dst4[s]);
                }
            }
            __builtin_amdgcn_sched_barrier(0);   // pin: DMAs before stores

            gather2(cur, c0);                    // 4 stores per thread

            __builtin_amdgcn_sched_barrier(0);   // pin: stores before wait

            if (p + 1 < nph) {
                // in-order vmcnt: count<=4 => the 2 oldest (our DMAs) retired;
                // the 4 output stores stay in flight across the barrier.
                asm volatile("s_waitcnt vmcnt(4)" ::: "memory");
                __builtin_amdgcn_sched_barrier(0);
                __builtin_amdgcn_s_barrier();
                __builtin_amdgcn_sched_barrier(0);
            }
            float* tmp = cur; cur = nxt; nxt = tmp;
            optr0 += (size_t)CGB * HW;
            optr1 += (size_t)CGB * HW;
        }
    } else {
        // generic slow path (partial tiles / W%4!=0): scalar stage + full syncs
        for (int p = 0; p < nph; ++p) {
            const int c0 = p * CGB;
            __syncthreads();
            for (int i = tid; i < CGB * PLANE; i += NTHREADS) {
                const int ch  = i / PLANE;
                const int rem = i - ch * PLANE;
                const int rr  = rem / LW;
                const int cc  = rem - rr * LW;
                const int yy  = min(max(gy0 + rr, 0), H - 1);
                const int xx  = min(max(gx0 + cc, 0), W - 1);
                const int chc = min(c0 + ch, C - 1);
                lds[i] = img[(size_t)chc * HW + (size_t)yy * W + xx];
            }
            __syncthreads();
            gather2(&lds[0], c0);
            optr0 += (size_t)CGB * HW;
            optr1 += (size_t)CGB * HW;
        }
    }
}

extern "C" void kernel_launch(void* const* d_in, const int* in_sizes, int n_in,
                              void* d_out, int out_size, void* d_ws, size_t ws_size,
                              hipStream_t stream) {
    const float* img  = (const float*)d_in[0];
    const float* flow = (const float*)d_in[1];
    const int*   Hp   = (const int*)d_in[2];
    const int*   Wp   = (const int*)d_in[3];
    float* out = (float*)d_out;

    const int HW = in_sizes[1] / 2;    // flow is (1,2,H,W)
    const int C  = in_sizes[0] / HW;   // img is (1,C,H,W)

    // host doesn't know W,H (device scalars): launch with tile slack,
    // excess blocks exit on the in-kernel ntiles guard.
    const int grid = (HW + TSX * TSY - 1) / (TSX * TSY) + 64;
    warp_pipe3<<<grid, NTHREADS, 0, stream>>>(img, flow, Hp, Wp, out, HW, C);
}